// Round 1
// baseline (24165.211 us; speedup 1.0000x reference)
//
#include <hip/hip_runtime.h>
#include <hip/hip_bf16.h>

#define TT 1024
#define BB 64
#define II 256
#define HH 512
#define OO 128

typedef __attribute__((ext_vector_type(4))) float f32x4;
typedef __attribute__((ext_vector_type(8))) __bf16 bf16x8;
typedef __attribute__((ext_vector_type(8))) short s16x8;
typedef unsigned short u16;

static __device__ __forceinline__ bf16x8 ldb8(const u16* p) {
    s16x8 v = *reinterpret_cast<const s16x8*>(p);
    return __builtin_bit_cast(bf16x8, v);
}
static __device__ __forceinline__ u16 f2b(float f) {
    return __builtin_bit_cast(u16, (__bf16)f);
}
static __device__ __forceinline__ float b2f(u16 u) {
    return (float)__builtin_bit_cast(__bf16, u);
}

// fp32 -> bf16 conversion (weights once per launch, initial states)
__global__ void cvt_kernel(const float* __restrict__ src, u16* __restrict__ dst, int n) {
    int i = blockIdx.x * blockDim.x + threadIdx.x;
    if (i < n) dst[i] = f2b(src[i]);
}

// One pipelined "super-step": blocks 0..7 compute h0[t] (if t<TT),
// blocks 8..15 compute h1[t-1] (if t>=1). Both only READ h0[t-1]; writes
// are to disjoint parity buffers, so no intra-kernel ordering is needed.
// Kernel boundaries give cross-step visibility (agent-scope release/acquire).
__global__ __launch_bounds__(512) void step_kernel(
    int t, const float* __restrict__ x,
    const u16* __restrict__ Wih0, const u16* __restrict__ Whh0,
    const u16* __restrict__ Wih1, const u16* __restrict__ Whh1,
    const float* __restrict__ bih0, const float* __restrict__ bhh0,
    const float* __restrict__ bih1, const float* __restrict__ bhh1,
    u16* __restrict__ h0buf, u16* __restrict__ h1buf)
{
    const int tid = threadIdx.x;
    const int l  = tid & 63, w = tid >> 6;   // lane, wave (8 waves)
    const int lm = l & 15,  lg = l >> 4;
    const int mt = w & 3;                    // M-tile (batch rows 16*mt..)
    const int ntb = (w >> 2) * 2;            // N-tile pair base (0 or 2)
    const int m  = mt * 16 + lm;             // batch row this lane loads A for
    const int kb = lg * 8;                   // k offset within 32-slice
    const int bx = blockIdx.x;

    f32x4 acc0 = {0.f, 0.f, 0.f, 0.f};
    f32x4 acc1 = {0.f, 0.f, 0.f, 0.f};

    if (bx < 8) {
        // ---- layer 0, step t: h0[t] = tanh([x_t | h0[t-1]] @ [Wih0;Whh0]^T + b)
        if (t >= TT) return;
        const int p = t & 1;
        const int n_0 = bx * 64 + ntb * 16 + lm;  // absolute output col (B-frag row of W)
        const int n_1 = n_0 + 16;
        const float* xrow  = x + (size_t)m * (TT * II) + (size_t)t * II;
        const u16*   hprev = h0buf + (p ^ 1) * (BB * HH) + m * HH;

        #pragma unroll
        for (int kt = 0; kt < 8; ++kt) {          // K = 0..255  (x part, fp32->bf16)
            const int k = kt * 32 + kb;
            f32x4 x0 = *reinterpret_cast<const f32x4*>(xrow + k);
            f32x4 x1 = *reinterpret_cast<const f32x4*>(xrow + k + 4);
            bf16x8 a;
            a[0]=(__bf16)x0[0]; a[1]=(__bf16)x0[1]; a[2]=(__bf16)x0[2]; a[3]=(__bf16)x0[3];
            a[4]=(__bf16)x1[0]; a[5]=(__bf16)x1[1]; a[6]=(__bf16)x1[2]; a[7]=(__bf16)x1[3];
            bf16x8 b0 = ldb8(Wih0 + n_0 * II + k);
            bf16x8 b1 = ldb8(Wih0 + n_1 * II + k);
            acc0 = __builtin_amdgcn_mfma_f32_16x16x32_bf16(a, b0, acc0, 0, 0, 0);
            acc1 = __builtin_amdgcn_mfma_f32_16x16x32_bf16(a, b1, acc1, 0, 0, 0);
        }
        #pragma unroll
        for (int kt = 0; kt < 16; ++kt) {         // K = 256..767 (h0[t-1] part)
            const int k = kt * 32 + kb;
            bf16x8 a  = ldb8(hprev + k);
            bf16x8 b0 = ldb8(Whh0 + n_0 * HH + k);
            bf16x8 b1 = ldb8(Whh0 + n_1 * HH + k);
            acc0 = __builtin_amdgcn_mfma_f32_16x16x32_bf16(a, b0, acc0, 0, 0, 0);
            acc1 = __builtin_amdgcn_mfma_f32_16x16x32_bf16(a, b1, acc1, 0, 0, 0);
        }
        u16* hout = h0buf + p * (BB * HH);
        const float bia0 = bih0[n_0] + bhh0[n_0];
        const float bia1 = bih0[n_1] + bhh0[n_1];
        #pragma unroll
        for (int r = 0; r < 4; ++r) {             // C/D: col=lane&15, row=(lane>>4)*4+r
            const int mo = mt * 16 + lg * 4 + r;
            hout[mo * HH + n_0] = f2b(tanhf(acc0[r] + bia0));
            hout[mo * HH + n_1] = f2b(tanhf(acc1[r] + bia1));
        }
    } else {
        // ---- layer 1, step s=t-1: h1[s] = tanh([h0[s] | h1[s-1]] @ [Wih1;Whh1]^T + b)
        if (t < 1) return;
        const int s  = t - 1;
        const int ps = s & 1;
        const int n_0 = (bx - 8) * 64 + ntb * 16 + lm;
        const int n_1 = n_0 + 16;
        const u16* h0s = h0buf + (ps) * (BB * HH) + m * HH;       // h0[s], parity s&1
        const u16* h1p = h1buf + (ps ^ 1) * (BB * HH) + m * HH;   // h1[s-1]

        #pragma unroll
        for (int kt = 0; kt < 16; ++kt) {         // K = 0..511 (h0[s] @ Wih1^T)
            const int k = kt * 32 + kb;
            bf16x8 a  = ldb8(h0s + k);
            bf16x8 b0 = ldb8(Wih1 + n_0 * HH + k);
            bf16x8 b1 = ldb8(Wih1 + n_1 * HH + k);
            acc0 = __builtin_amdgcn_mfma_f32_16x16x32_bf16(a, b0, acc0, 0, 0, 0);
            acc1 = __builtin_amdgcn_mfma_f32_16x16x32_bf16(a, b1, acc1, 0, 0, 0);
        }
        #pragma unroll
        for (int kt = 0; kt < 16; ++kt) {         // K = 512..1023 (h1[s-1] @ Whh1^T)
            const int k = kt * 32 + kb;
            bf16x8 a  = ldb8(h1p + k);
            bf16x8 b0 = ldb8(Whh1 + n_0 * HH + k);
            bf16x8 b1 = ldb8(Whh1 + n_1 * HH + k);
            acc0 = __builtin_amdgcn_mfma_f32_16x16x32_bf16(a, b0, acc0, 0, 0, 0);
            acc1 = __builtin_amdgcn_mfma_f32_16x16x32_bf16(a, b1, acc1, 0, 0, 0);
        }
        u16* hout = h1buf + ps * (BB * HH);
        const float bia0 = bih1[n_0] + bhh1[n_0];
        const float bia1 = bih1[n_1] + bhh1[n_1];
        #pragma unroll
        for (int r = 0; r < 4; ++r) {
            const int mo = mt * 16 + lg * 4 + r;
            hout[mo * HH + n_0] = f2b(tanhf(acc0[r] + bia0));
            hout[mo * HH + n_1] = f2b(tanhf(acc1[r] + bia1));
        }
    }
}

// out[b][o] = h1[T-1][b] . W_out[o] + b_out[o]   (fp32 accumulate)
__global__ __launch_bounds__(128) void head_kernel(
    const u16* __restrict__ h1last, const float* __restrict__ Wout,
    const float* __restrict__ bout, float* __restrict__ out)
{
    __shared__ float hrow[HH];
    const int b = blockIdx.x;
    const int o = threadIdx.x;  // 0..127
    for (int k = o; k < HH; k += 128) hrow[k] = b2f(h1last[b * HH + k]);
    __syncthreads();
    float acc = 0.f;
    const float* wr = Wout + o * HH;
    #pragma unroll 4
    for (int k = 0; k < HH; ++k) acc += hrow[k] * wr[k];
    out[b * OO + o] = acc + bout[o];
}

extern "C" void kernel_launch(void* const* d_in, const int* in_sizes, int n_in,
                              void* d_out, int out_size, void* d_ws, size_t ws_size,
                              hipStream_t stream) {
    const float* x      = (const float*)d_in[0];
    const float* h0init = (const float*)d_in[1];   // [2][64][512], layer0 then layer1
    const float* W_ih0  = (const float*)d_in[2];
    const float* b_ih0  = (const float*)d_in[3];
    const float* W_hh0  = (const float*)d_in[4];
    const float* b_hh0  = (const float*)d_in[5];
    const float* W_ih1  = (const float*)d_in[6];
    const float* b_ih1  = (const float*)d_in[7];
    const float* W_hh1  = (const float*)d_in[8];
    const float* b_hh1  = (const float*)d_in[9];
    const float* W_out  = (const float*)d_in[10];
    const float* b_out  = (const float*)d_in[11];
    float* out = (float*)d_out;

    // workspace layout (u16 elements)
    u16* ws      = (u16*)d_ws;
    u16* Wb_ih0  = ws;                         // 512*256
    u16* Wb_hh0  = Wb_ih0 + 512 * 256;         // 512*512
    u16* Wb_ih1  = Wb_hh0 + 512 * 512;         // 512*512
    u16* Wb_hh1  = Wb_ih1 + 512 * 512;         // 512*512
    u16* h0buf   = Wb_hh1 + 512 * 512;         // 2 * 64*512 (parity double buffer)
    u16* h1buf   = h0buf + 2 * BB * HH;        // 2 * 64*512

    const int thr = 256;
    cvt_kernel<<<(512 * 256 + thr - 1) / thr, thr, 0, stream>>>(W_ih0, Wb_ih0, 512 * 256);
    cvt_kernel<<<(512 * 512 + thr - 1) / thr, thr, 0, stream>>>(W_hh0, Wb_hh0, 512 * 512);
    cvt_kernel<<<(512 * 512 + thr - 1) / thr, thr, 0, stream>>>(W_ih1, Wb_ih1, 512 * 512);
    cvt_kernel<<<(512 * 512 + thr - 1) / thr, thr, 0, stream>>>(W_hh1, Wb_hh1, 512 * 512);
    // initial states go into the parity-1 slots (read at t=0 / s=0)
    cvt_kernel<<<(BB * HH + thr - 1) / thr, thr, 0, stream>>>(h0init, h0buf + BB * HH, BB * HH);
    cvt_kernel<<<(BB * HH + thr - 1) / thr, thr, 0, stream>>>(h0init + BB * HH, h1buf + BB * HH, BB * HH);

    for (int t = 0; t <= TT; ++t) {
        step_kernel<<<16, 512, 0, stream>>>(t, x, Wb_ih0, Wb_hh0, Wb_ih1, Wb_hh1,
                                            b_ih0, b_hh0, b_ih1, b_hh1, h0buf, h1buf);
    }
    // h1[T-1] lives in parity (T-1)&1 == 1
    head_kernel<<<BB, 128, 0, stream>>>(h1buf + BB * HH, W_out, b_out, out);
}

// Round 2
// 12302.227 us; speedup vs baseline: 1.9643x; 1.9643x over previous
//
#include <hip/hip_runtime.h>
#include <hip/hip_bf16.h>

#define TT 1024
#define BB 64
#define II 256
#define HH 512
#define OO 128

typedef __attribute__((ext_vector_type(4))) float f32x4;
typedef __attribute__((ext_vector_type(4))) int   i32x4;
typedef __attribute__((ext_vector_type(8))) __bf16 bf16x8;
typedef unsigned long long u64;
typedef unsigned short u16;
typedef unsigned int u32;

#define RED_OFF  131072
#define SMEM_BYTES (131072 + 16384)   // A-stage (max 128KB) + reduce scratch 16KB

static __device__ __forceinline__ u16 f2b(float f) { return __builtin_bit_cast(u16, (__bf16)f); }
static __device__ __forceinline__ float b2f(u16 u) { return (float)__builtin_bit_cast(__bf16, u); }

static __device__ __forceinline__ u64 pack4f(float a, float b, float c, float d) {
    return (u64)f2b(a) | ((u64)f2b(b) << 16) | ((u64)f2b(c) << 32) | ((u64)f2b(d) << 48);
}

static __device__ __forceinline__ void spin_ge(int* c, int tgt) {
    while (__hip_atomic_load(c, __ATOMIC_RELAXED, __HIP_MEMORY_SCOPE_AGENT) < tgt)
        __builtin_amdgcn_s_sleep(1);
}
static __device__ __forceinline__ u64 ald(const u64* p) {
    return __hip_atomic_load(p, __ATOMIC_RELAXED, __HIP_MEMORY_SCOPE_AGENT);
}
static __device__ __forceinline__ void ast(u64* p, u64 v) {
    __hip_atomic_store(p, v, __ATOMIC_RELAXED, __HIP_MEMORY_SCOPE_AGENT);
}

// Persistent per-layer worker. 8 blocks per layer; block owns a 64-col slice.
// Counters are sum-gated: cntX >= 8*u  <=>  all 8 blocks of group X completed
// unit u-1 (unit 0 = init round, unit t+1 = step t). h buffers are 4-deep.
template <int L>
static __device__ void run_layer(const float* __restrict__ x,
                                 const float* __restrict__ hinit,
                                 const float* __restrict__ Wi,
                                 const float* __restrict__ Wh,
                                 const float* __restrict__ bi,
                                 const float* __restrict__ bh,
                                 int* cnt0, int* cnt1,
                                 u64* h0s, u64* h1s,
                                 int nb, char* smem)
{
    constexpr int KT = (L == 0) ? 24 : 32;   // K-tiles of 32 (L0: 8 x-tiles + 16 h-tiles)
    constexpr int KH = KT / 2;               // per-wave K-half
    constexpr int NFRAG = 4 * KT * 64;
    constexpr int FPT = NFRAG / 512;

    const int tid = threadIdx.x;
    const int l = tid & 63, w = tid >> 6;
    const int lm = l & 15, lg = l >> 4;
    const int wn = w & 1, wm = (w >> 1) & 1, wk = w >> 2;

    u64* wbase = (L == 0) ? h0s : h1s;

    // ---- init round: write initial hidden state slice into slot 3 (= step -1)
    #pragma unroll
    for (int h = 0; h < 2; ++h) {
        const int q = h * 512 + tid;
        const int m = q >> 4, uc = q & 15;
        const float* s = hinit + (size_t)m * HH + nb + uc * 4;
        ast(&wbase[3 * 8192 + m * 128 + (nb >> 2) + uc], pack4f(s[0], s[1], s[2], s[3]));
    }
    __syncthreads();
    if (tid == 0) {
        __builtin_amdgcn_fence(__ATOMIC_RELEASE, "agent");
        __hip_atomic_fetch_add((L == 0) ? cnt0 : cnt1, 1, __ATOMIC_RELAXED, __HIP_MEMORY_SCOPE_AGENT);
    }

    // ---- B fragments (weights) -> registers, bf16, resident for whole kernel
    bf16x8 B[2][KH];
    #pragma unroll
    for (int j = 0; j < 2; ++j) {
        const int n = nb + (2 * wn + j) * 16 + lm;
        #pragma unroll
        for (int q = 0; q < KH; ++q) {
            const int kt = wk * KH + q;
            const float* src;
            if (L == 0) src = (kt < 8) ? (Wi + (size_t)n * II + kt * 32 + lg * 8)
                                       : (Wh + (size_t)n * HH + (kt - 8) * 32 + lg * 8);
            else        src = (kt < 16) ? (Wi + (size_t)n * HH + kt * 32 + lg * 8)
                                        : (Wh + (size_t)n * HH + (kt - 16) * 32 + lg * 8);
            f32x4 a0 = *reinterpret_cast<const f32x4*>(src);
            f32x4 a1 = *reinterpret_cast<const f32x4*>(src + 4);
            bf16x8 v;
            v[0]=(__bf16)a0[0]; v[1]=(__bf16)a0[1]; v[2]=(__bf16)a0[2]; v[3]=(__bf16)a0[3];
            v[4]=(__bf16)a1[0]; v[5]=(__bf16)a1[1]; v[6]=(__bf16)a1[2]; v[7]=(__bf16)a1[3];
            B[j][q] = v;
        }
    }
    float bs[2];
    #pragma unroll
    for (int j = 0; j < 2; ++j) {
        const int n = nb + (2 * wn + j) * 16 + lm;
        bs[j] = bi[n] + bh[n];
    }

    i32x4* astage = (i32x4*)smem;

    for (int t = 0; t < TT; ++t) {
        // ---- wait for producers (and buffer-overwrite safety)
        if (tid == 0) {
            if (L == 0) {
                spin_ge(cnt0, 8 * (t + 1));          // h0[t-1] ready
                if (t >= 3) spin_ge(cnt1, 8 * (t - 2)); // L1 done reading h0[t-4]
            } else {
                spin_ge(cnt0, 8 * (t + 2));          // h0[t] ready
                spin_ge(cnt1, 8 * (t + 1));          // h1[t-1] ready
            }
        }
        __syncthreads();
        __builtin_amdgcn_fence(__ATOMIC_ACQUIRE, "agent");

        // ---- stage A fragments into LDS in MFMA-fragment-linear order
        const u64* r0 = h0s + ((L == 0 ? (t + 3) : t) & 3) * 8192;
        const u64* r1 = h1s + ((t + 3) & 3) * 8192;
        #pragma unroll
        for (int ff = 0; ff < FPT; ++ff) {
            const int f = ff * 512 + tid;
            const int mt = f / (KT * 64);
            const int kt = (f >> 6) % KT;
            const int ll = f & 63;
            const int m = mt * 16 + (ll & 15);
            const int k8 = (ll >> 4) * 8;
            i32x4 v;
            if (L == 0 && kt < 8) {
                const float* s = x + ((size_t)m * TT + t) * II + kt * 32 + k8;
                f32x4 a0 = *reinterpret_cast<const f32x4*>(s);
                f32x4 a1 = *reinterpret_cast<const f32x4*>(s + 4);
                bf16x8 bv;
                bv[0]=(__bf16)a0[0]; bv[1]=(__bf16)a0[1]; bv[2]=(__bf16)a0[2]; bv[3]=(__bf16)a0[3];
                bv[4]=(__bf16)a1[0]; bv[5]=(__bf16)a1[1]; bv[6]=(__bf16)a1[2]; bv[7]=(__bf16)a1[3];
                v = __builtin_bit_cast(i32x4, bv);
            } else {
                const u64* src; int koff;
                if (L == 0)      { src = r0; koff = (kt - 8) * 32 + k8; }
                else if (kt < 16){ src = r0; koff = kt * 32 + k8; }
                else             { src = r1; koff = (kt - 16) * 32 + k8; }
                const u64* p = src + ((size_t)m * HH + koff) / 4;
                u64 u0 = ald(p), u1 = ald(p + 1);
                v[0] = (int)(u32)u0; v[1] = (int)(u32)(u0 >> 32);
                v[2] = (int)(u32)u1; v[3] = (int)(u32)(u1 >> 32);
            }
            astage[f] = v;
        }
        __syncthreads();

        // ---- MFMA over this wave's K-half (B from registers, A from LDS)
        f32x4 acc[2][2] = {{{0,0,0,0},{0,0,0,0}},{{0,0,0,0},{0,0,0,0}}};
        #pragma unroll
        for (int q = 0; q < KH; ++q) {
            const int kt = wk * KH + q;
            #pragma unroll
            for (int i = 0; i < 2; ++i) {
                const int mt = 2 * wm + i;
                bf16x8 a = __builtin_bit_cast(bf16x8, astage[(mt * KT + kt) * 64 + l]);
                acc[i][0] = __builtin_amdgcn_mfma_f32_16x16x32_bf16(a, B[0][q], acc[i][0], 0, 0, 0);
                acc[i][1] = __builtin_amdgcn_mfma_f32_16x16x32_bf16(a, B[1][q], acc[i][1], 0, 0, 0);
            }
        }

        // ---- cross-wave K reduction; biased sums -> smem[0..16KB) (A-stage is dead)
        f32x4* red = (f32x4*)(smem + RED_OFF);
        if (wk == 1) {
            const int base = ((w - 4) * 64 + l) * 4;
            red[base + 0] = acc[0][0]; red[base + 1] = acc[0][1];
            red[base + 2] = acc[1][0]; red[base + 3] = acc[1][1];
        }
        __syncthreads();
        if (wk == 0) {
            const int base = (w * 64 + l) * 4;
            acc[0][0] += red[base + 0]; acc[0][1] += red[base + 1];
            acc[1][0] += red[base + 2]; acc[1][1] += red[base + 3];
            float* sum = (float*)smem;
            #pragma unroll
            for (int i = 0; i < 2; ++i) {
                #pragma unroll
                for (int j = 0; j < 2; ++j) {
                    const int c = (2 * wn + j) * 16 + lm;
                    #pragma unroll
                    for (int r = 0; r < 4; ++r) {
                        const int m = (2 * wm + i) * 16 + lg * 4 + r;
                        sum[m * 64 + c] = acc[i][j][r] + bs[j];
                    }
                }
            }
        }
        __syncthreads();

        // ---- tanh + pack + coherent store (all 512 threads)
        u64* wslot = wbase + (t & 3) * 8192;
        const float* sum = (const float*)smem;
        #pragma unroll
        for (int h = 0; h < 2; ++h) {
            const int q = h * 512 + tid;
            f32x4 v = *reinterpret_cast<const f32x4*>(sum + q * 4);
            const int m = q >> 4, uc = q & 15;
            ast(&wslot[m * 128 + (nb >> 2) + uc],
                pack4f(tanhf(v[0]), tanhf(v[1]), tanhf(v[2]), tanhf(v[3])));
        }
        __syncthreads();   // drains each thread's stores (vmcnt) before signal
        if (tid == 0) {
            __builtin_amdgcn_fence(__ATOMIC_RELEASE, "agent");
            __hip_atomic_fetch_add((L == 0) ? cnt0 : cnt1, 1, __ATOMIC_RELAXED, __HIP_MEMORY_SCOPE_AGENT);
        }
    }
}

// Final Linear head on h1[T-1]; done by the 8 layer-1 blocks (16 out-cols each).
static __device__ void head_phase(const float* __restrict__ Wout,
                                  const float* __restrict__ bout,
                                  const u64* __restrict__ h1slot,
                                  float* __restrict__ out,
                                  int obase, int* cnt1, char* smem)
{
    const int tid = threadIdx.x;
    if (tid == 0) spin_ge(cnt1, 8 * (TT + 1));
    __syncthreads();
    __builtin_amdgcn_fence(__ATOMIC_ACQUIRE, "agent");
    float* hf = (float*)smem;                 // [64][516] padded f32
    for (int q = tid; q < 8192; q += 512) {
        u64 v = ald(&h1slot[q]);
        const int m = q >> 7, c4 = (q & 127) * 4;
        float* d = hf + m * 516 + c4;
        d[0] = b2f((u16)v);         d[1] = b2f((u16)(v >> 16));
        d[2] = b2f((u16)(v >> 32)); d[3] = b2f((u16)(v >> 48));
    }
    __syncthreads();
    const int b = tid >> 3, oo = tid & 7;
    const float* hrow = hf + b * 516;
    #pragma unroll
    for (int h = 0; h < 2; ++h) {
        const int o = obase + oo + h * 8;
        const float* wr = Wout + (size_t)o * HH;
        float acc = 0.f;
        #pragma unroll 4
        for (int k4 = 0; k4 < 128; ++k4) {
            f32x4 wv = *reinterpret_cast<const f32x4*>(wr + k4 * 4);
            f32x4 hv = *reinterpret_cast<const f32x4*>(hrow + k4 * 4);
            acc += wv[0]*hv[0] + wv[1]*hv[1] + wv[2]*hv[2] + wv[3]*hv[3];
        }
        out[b * OO + o] = acc + bout[o];
    }
}

__global__ __launch_bounds__(512, 2) void rnn_persist(
    const float* __restrict__ x, const float* __restrict__ h0init,
    const float* __restrict__ Wih0, const float* __restrict__ bih0,
    const float* __restrict__ Whh0, const float* __restrict__ bhh0,
    const float* __restrict__ Wih1, const float* __restrict__ bih1,
    const float* __restrict__ Whh1, const float* __restrict__ bhh1,
    const float* __restrict__ Wout, const float* __restrict__ bout,
    float* __restrict__ out, int* __restrict__ cnt, u64* __restrict__ hbuf)
{
    __shared__ __align__(16) char smem[SMEM_BYTES];
    const int bx = blockIdx.x;
    int* cnt0 = cnt;
    int* cnt1 = cnt + 32;                    // separate cache line
    u64* h0s = hbuf;                          // 4 slots x 8192 ull
    u64* h1s = hbuf + 4 * 8192;
    if (bx < 8) {
        run_layer<0>(x, h0init, Wih0, Whh0, bih0, bhh0, cnt0, cnt1, h0s, h1s, bx * 64, smem);
    } else {
        run_layer<1>(nullptr, h0init + BB * HH, Wih1, Whh1, bih1, bhh1,
                     cnt0, cnt1, h0s, h1s, (bx - 8) * 64, smem);
        head_phase(Wout, bout, h1s + 3 * 8192, out, (bx - 8) * 16, cnt1, smem);
    }
}

extern "C" void kernel_launch(void* const* d_in, const int* in_sizes, int n_in,
                              void* d_out, int out_size, void* d_ws, size_t ws_size,
                              hipStream_t stream) {
    const float* x     = (const float*)d_in[0];
    const float* h0i   = (const float*)d_in[1];
    const float* Wih0  = (const float*)d_in[2];
    const float* bih0  = (const float*)d_in[3];
    const float* Whh0  = (const float*)d_in[4];
    const float* bhh0  = (const float*)d_in[5];
    const float* Wih1  = (const float*)d_in[6];
    const float* bih1  = (const float*)d_in[7];
    const float* Whh1  = (const float*)d_in[8];
    const float* bhh1  = (const float*)d_in[9];
    const float* Wout  = (const float*)d_in[10];
    const float* bout  = (const float*)d_in[11];
    float* out = (float*)d_out;
    int* cnt  = (int*)d_ws;
    u64* hbuf = (u64*)((char*)d_ws + 256);

    hipMemsetAsync(d_ws, 0, 256, stream);   // zero the counters every launch
    void* args[] = { &x, &h0i, &Wih0, &bih0, &Whh0, &bhh0, &Wih1, &bih1,
                     &Whh1, &bhh1, &Wout, &bout, &out, &cnt, &hbuf };
    hipLaunchCooperativeKernel((const void*)rnn_persist, dim3(16), dim3(512),
                               args, 0, stream);
}

// Round 3
// 8963.697 us; speedup vs baseline: 2.6959x; 1.3725x over previous
//
#include <hip/hip_runtime.h>
#include <hip/hip_bf16.h>

#define TT 1024
#define BB 64
#define II 256
#define HH 512
#define OO 128

typedef __attribute__((ext_vector_type(4))) float f32x4;
typedef __attribute__((ext_vector_type(4))) int   i32x4;
typedef __attribute__((ext_vector_type(8))) __bf16 bf16x8;
typedef __attribute__((ext_vector_type(8))) short s16x8;
typedef unsigned long long u64;
typedef unsigned short u16;
typedef unsigned int u32;

// smem layout: A-stage frags at 0 (L0 64KB, L1 128KB); partials L0 @64KB, L1 @0
// (overlaid on dead A-frags, guarded by a barrier); head scratch 132096B; bias @132096.
#define BIAS_OFF 132096
#define SMEM_BYTES 132608

static __device__ __forceinline__ u16 f2b(float f) { return __builtin_bit_cast(u16, (__bf16)f); }
static __device__ __forceinline__ float b2f(u16 u) { return (float)__builtin_bit_cast(__bf16, u); }

static __device__ __forceinline__ u64 pack4f(float a, float b, float c, float d) {
    return (u64)f2b(a) | ((u64)f2b(b) << 16) | ((u64)f2b(c) << 32) | ((u64)f2b(d) << 48);
}
static __device__ __forceinline__ bf16x8 cvt8(f32x4 a0, f32x4 a1) {
    bf16x8 v;
    v[0]=(__bf16)a0[0]; v[1]=(__bf16)a0[1]; v[2]=(__bf16)a0[2]; v[3]=(__bf16)a0[3];
    v[4]=(__bf16)a1[0]; v[5]=(__bf16)a1[1]; v[6]=(__bf16)a1[2]; v[7]=(__bf16)a1[3];
    return v;
}
static __device__ __forceinline__ void spin_ge(int* c, int tgt) {
    while (__hip_atomic_load(c, __ATOMIC_RELAXED, __HIP_MEMORY_SCOPE_AGENT) < tgt)
        __builtin_amdgcn_s_sleep(1);
}
static __device__ __forceinline__ u64 ald(const u64* p) {
    return __hip_atomic_load(p, __ATOMIC_RELAXED, __HIP_MEMORY_SCOPE_AGENT);
}
static __device__ __forceinline__ void ast(u64* p, u64 v) {
    __hip_atomic_store(p, v, __ATOMIC_RELAXED, __HIP_MEMORY_SCOPE_AGENT);
}

// ---------------- Phase A: XB[t][b][n] = x_t @ W_ih0^T + b_ih0 + b_hh0 (bf16) ----
// Operand-swapped MFMA (A=W rows, B=x rows) so the 4 output elems per acc reg are
// CONSECUTIVE n -> packed u64 stores.
__global__ __launch_bounds__(512, 2) void xproj_kernel(
    const float* __restrict__ x, const float* __restrict__ Wih0,
    const float* __restrict__ bih0, const float* __restrict__ bhh0,
    u64* __restrict__ XBu)
{
    const int tid = threadIdx.x;
    const int l = tid & 63, w = tid >> 6;
    const int lm = l & 15, lg = l >> 4;
    const int t = blockIdx.x * 4 + (w >> 1);
    const int nh = w & 1;                      // n-half (256 cols)

    bf16x8 xf[4][8];                           // B-operand: x rows (b), K=256
    #pragma unroll
    for (int bt = 0; bt < 4; ++bt) {
        const float* xb = x + (size_t)(bt * 16 + lm) * (TT * II) + (size_t)t * II + lg * 8;
        #pragma unroll
        for (int kt = 0; kt < 8; ++kt) {
            f32x4 a0 = *(const f32x4*)(xb + kt * 32);
            f32x4 a1 = *(const f32x4*)(xb + kt * 32 + 4);
            xf[bt][kt] = cvt8(a0, a1);
        }
    }
    for (int nt = 0; nt < 16; ++nt) {
        const int n_row = nh * 256 + nt * 16 + lm;
        bf16x8 wf[8];                          // A-operand: W rows (n)
        #pragma unroll
        for (int kt = 0; kt < 8; ++kt) {
            const float* wsrc = Wih0 + (size_t)n_row * II + kt * 32 + lg * 8;
            f32x4 a0 = *(const f32x4*)(wsrc);
            f32x4 a1 = *(const f32x4*)(wsrc + 4);
            wf[kt] = cvt8(a0, a1);
        }
        f32x4 acc[4] = {{0,0,0,0},{0,0,0,0},{0,0,0,0},{0,0,0,0}};
        #pragma unroll
        for (int kt = 0; kt < 8; ++kt)
            #pragma unroll
            for (int bt = 0; bt < 4; ++bt)
                acc[bt] = __builtin_amdgcn_mfma_f32_16x16x32_bf16(wf[kt], xf[bt][kt], acc[bt], 0, 0, 0);
        const int n0 = nh * 256 + nt * 16 + lg * 4;   // D row = n (A-operand), 4 consecutive
        f32x4 bias = *(const f32x4*)(bih0 + n0);
        f32x4 bias2 = *(const f32x4*)(bhh0 + n0);
        #pragma unroll
        for (int bt = 0; bt < 4; ++bt) {
            const int b = bt * 16 + lm;               // D col = b (B-operand)
            XBu[((size_t)t * 64 + b) * 128 + (n0 >> 2)] =
                pack4f(acc[bt][0] + bias[0] + bias2[0], acc[bt][1] + bias[1] + bias2[1],
                       acc[bt][2] + bias[2] + bias2[2], acc[bt][3] + bias[3] + bias2[3]);
        }
    }
}

// ---------------- Phase B: persistent recurrent workers ------------------------
// 16 blocks: 0-7 = layer0 (n-slice 64 each), 8-15 = layer1. Weights live in VGPRs.
// h exchange: 4-deep slots of [64][128 u64] in ws, agent-scope atomics + counters.
template <int L>
static __device__ void run_layer(const u16* __restrict__ XB,
                                 const float* __restrict__ hinit,
                                 const float* __restrict__ Wi,   // L0: Whh0; L1: Wih1
                                 const float* __restrict__ Wh,   // L1: Whh1
                                 const float* __restrict__ bi, const float* __restrict__ bh,
                                 int* cnt0, int* cnt1,
                                 u64* h0s, u64* h1s,
                                 int nb, char* smem)
{
    constexpr int KT = (L == 0) ? 16 : 32;     // K/32
    constexpr int NGRP = (L == 0) ? 1 : 2;     // staged matrices
    constexpr int MTW = (L == 0) ? 1 : 2;      // m-tiles per wave
    constexpr int WKG = (L == 0) ? 2 : 4;      // K-split groups
    constexpr int PART_OFF = (L == 0) ? 65536 : 0;

    const int tid = threadIdx.x;
    const int l = tid & 63, w = tid >> 6;
    const int lm = l & 15, lg = l >> 4;
    const int wm = (L == 0) ? (w & 3) : (w & 1);
    const int wk = (L == 0) ? (w >> 2) : (w >> 1);
    u64* wbase = (L == 0) ? h0s : h1s;
    int* mycnt = (L == 0) ? cnt0 : cnt1;

    // ---- init: write initial hidden slice (cols [nb,nb+64)) into slot 3
    {
        const int m = tid >> 3, c0 = (tid & 7) * 8;
        const float* s = hinit + (size_t)m * HH + nb + c0;
        u64* d = &wbase[3 * 8192 + m * 128 + (nb >> 2) + (tid & 7) * 2];
        ast(&d[0], pack4f(s[0], s[1], s[2], s[3]));
        ast(&d[1], pack4f(s[4], s[5], s[6], s[7]));
    }
    if (L == 1 && tid < 64) {
        float* bias_l = (float*)(smem + BIAS_OFF);
        bias_l[tid] = bi[nb + tid] + bh[nb + tid];
    }
    __syncthreads();
    if (tid == 0) {
        __builtin_amdgcn_fence(__ATOMIC_RELEASE, "agent");
        __hip_atomic_fetch_add(mycnt, 1, __ATOMIC_RELAXED, __HIP_MEMORY_SCOPE_AGENT);
    }

    // ---- B-fragments (weights) -> registers, zero-duplication partition
    bf16x8 B[4][8];
    #pragma unroll
    for (int nt = 0; nt < 4; ++nt) {
        const int n = nb + nt * 16 + lm;
        #pragma unroll
        for (int ktl = 0; ktl < 8; ++ktl) {
            const int ktg = wk * 8 + ktl;
            const float* src;
            if (L == 0) src = Wi + (size_t)n * HH + ktg * 32 + lg * 8;
            else        src = (ktg < 16) ? (Wi + (size_t)n * HH + ktg * 32 + lg * 8)
                                         : (Wh + (size_t)n * HH + (ktg - 16) * 32 + lg * 8);
            f32x4 a0 = *(const f32x4*)(src);
            f32x4 a1 = *(const f32x4*)(src + 4);
            B[nt][ktl] = cvt8(a0, a1);
        }
    }

    for (int t = 0; t < TT; ++t) {
        if (tid == 0) {
            if (L == 0) {
                spin_ge(cnt0, 8 * (t + 1));            // h0[t-1] ready
                if (t >= 4) spin_ge(cnt1, 8 * (t - 2)); // L1 done reading h0[t-4]
            } else {
                spin_ge(cnt0, 8 * (t + 2));            // h0[t] ready
                spin_ge(cnt1, 8 * (t + 1));            // h1[t-1] ready
            }
        }
        __syncthreads();
        __builtin_amdgcn_fence(__ATOMIC_ACQUIRE, "agent");

        // ---- stage full A matrices into LDS fragment layout (batched loads)
        const u64* src0 = h0s + ((L == 0 ? (t + 3) : t) & 3) * 8192;
        const u64* src1 = h1s + ((t + 3) & 3) * 8192;
        #pragma unroll
        for (int g = 0; g < NGRP; ++g) {
            const u64* sp = (g == 0) ? src0 : src1;
            i32x4 tmp[8];
            #pragma unroll
            for (int p = 0; p < 8; ++p) {
                const int s = p * 512 + tid;
                const int m = s & 63, c = s >> 6;
                tmp[p] = *(const i32x4*)(sp + m * 128 + c * 2);
            }
            #pragma unroll
            for (int p = 0; p < 8; ++p) {
                const int s = p * 512 + tid;
                const int m = s & 63, c = s >> 6;
                const int fa = (m >> 4) * KT + g * 16 + (c >> 2);
                const int ll = ((c & 3) << 4) | (m & 15);
                *(i32x4*)(smem + fa * 1024 + ll * 16) = tmp[p];
            }
        }
        __syncthreads();

        // ---- MFMA: A from LDS (x1 redundancy), B from registers
        f32x4 acc[MTW][4];
        #pragma unroll
        for (int i = 0; i < MTW; ++i)
            #pragma unroll
            for (int nt = 0; nt < 4; ++nt) acc[i][nt] = f32x4{0, 0, 0, 0};
        #pragma unroll
        for (int ktl = 0; ktl < 8; ++ktl) {
            #pragma unroll
            for (int i = 0; i < MTW; ++i) {
                const int fa = (wm * MTW + i) * KT + wk * 8 + ktl;
                bf16x8 a = *(const bf16x8*)(smem + fa * 1024 + l * 16);
                #pragma unroll
                for (int nt = 0; nt < 4; ++nt)
                    acc[i][nt] = __builtin_amdgcn_mfma_f32_16x16x32_bf16(a, B[nt][ktl], acc[i][nt], 0, 0, 0);
            }
        }
        if (L == 1) __syncthreads();   // partials overlay the A-region for L1

        // ---- write K-partials
        float* part = (float*)(smem + PART_OFF);
        #pragma unroll
        for (int i = 0; i < MTW; ++i)
            #pragma unroll
            for (int nt = 0; nt < 4; ++nt)
                #pragma unroll
                for (int r = 0; r < 4; ++r) {
                    const int m = (wm * MTW + i) * 16 + lg * 4 + r;
                    part[(wk * 64 + m) * 64 + nt * 16 + lm] = acc[i][nt][r];
                }
        __syncthreads();

        // ---- epilogue: reduce partials + bias/XB + tanh + pack + publish
        {
            const int m = tid >> 3, c0 = (tid & 7) * 8;
            f32x4 sa = {0, 0, 0, 0}, sb = {0, 0, 0, 0};
            #pragma unroll
            for (int k = 0; k < WKG; ++k) {
                const float* pr = part + (k * 64 + m) * 64 + c0;
                sa += *(const f32x4*)pr;
                sb += *(const f32x4*)(pr + 4);
            }
            float e[8];
            if (L == 0) {
                const s16x8 xv = *(const s16x8*)(XB + ((size_t)t * 64 + m) * 512 + nb + c0);
                #pragma unroll
                for (int r = 0; r < 4; ++r) {
                    e[r] = sa[r] + b2f((u16)xv[r]);
                    e[4 + r] = sb[r] + b2f((u16)xv[4 + r]);
                }
            } else {
                const float* bl = (const float*)(smem + BIAS_OFF) + c0;
                #pragma unroll
                for (int r = 0; r < 4; ++r) {
                    e[r] = sa[r] + bl[r];
                    e[4 + r] = sb[r] + bl[4 + r];
                }
            }
            u64* d = &wbase[(t & 3) * 8192 + m * 128 + (nb >> 2) + (tid & 7) * 2];
            ast(&d[0], pack4f(tanhf(e[0]), tanhf(e[1]), tanhf(e[2]), tanhf(e[3])));
            ast(&d[1], pack4f(tanhf(e[4]), tanhf(e[5]), tanhf(e[6]), tanhf(e[7])));
        }
        __syncthreads();
        if (tid == 0) {
            __builtin_amdgcn_fence(__ATOMIC_RELEASE, "agent");
            __hip_atomic_fetch_add(mycnt, 1, __ATOMIC_RELAXED, __HIP_MEMORY_SCOPE_AGENT);
        }
    }
}

// Final Linear head on h1[T-1]; 8 layer-1 blocks, 16 out-cols each.
static __device__ void head_phase(const float* __restrict__ Wout,
                                  const float* __restrict__ bout,
                                  const u64* __restrict__ h1slot,
                                  float* __restrict__ out,
                                  int obase, int* cnt1, char* smem)
{
    const int tid = threadIdx.x;
    if (tid == 0) spin_ge(cnt1, 8 * (TT + 1));
    __syncthreads();
    __builtin_amdgcn_fence(__ATOMIC_ACQUIRE, "agent");
    float* hf = (float*)smem;                 // [64][516] padded f32
    for (int q = tid; q < 8192; q += 512) {
        u64 v = ald(&h1slot[q]);
        const int m = q >> 7, c4 = (q & 127) * 4;
        float* d = hf + m * 516 + c4;
        d[0] = b2f((u16)v);         d[1] = b2f((u16)(v >> 16));
        d[2] = b2f((u16)(v >> 32)); d[3] = b2f((u16)(v >> 48));
    }
    __syncthreads();
    const int b = tid >> 3, oo = tid & 7;
    const float* hrow = hf + b * 516;
    #pragma unroll
    for (int h = 0; h < 2; ++h) {
        const int o = obase + oo + h * 8;
        const float* wr = Wout + (size_t)o * HH;
        float acc = 0.f;
        #pragma unroll 4
        for (int k4 = 0; k4 < 128; ++k4) {
            f32x4 wv = *(const f32x4*)(wr + k4 * 4);
            f32x4 hv = *(const f32x4*)(hrow + k4 * 4);
            acc += wv[0]*hv[0] + wv[1]*hv[1] + wv[2]*hv[2] + wv[3]*hv[3];
        }
        out[b * OO + o] = acc + bout[o];
    }
}

__global__ __launch_bounds__(512, 2) void rnn_persist(
    const u16* __restrict__ XB,
    const float* __restrict__ h0init,
    const float* __restrict__ Whh0,
    const float* __restrict__ Wih1, const float* __restrict__ bih1,
    const float* __restrict__ Whh1, const float* __restrict__ bhh1,
    const float* __restrict__ Wout, const float* __restrict__ bout,
    float* __restrict__ out, int* __restrict__ cnt, u64* __restrict__ hbuf)
{
    __shared__ __align__(16) char smem[SMEM_BYTES];
    const int bx = blockIdx.x;
    int* cnt0 = cnt;
    int* cnt1 = cnt + 32;
    u64* h0s = hbuf;
    u64* h1s = hbuf + 4 * 8192;
    if (bx < 8) {
        run_layer<0>(XB, h0init, Whh0, nullptr, nullptr, nullptr,
                     cnt0, cnt1, h0s, h1s, bx * 64, smem);
    } else {
        run_layer<1>(nullptr, h0init + BB * HH, Wih1, Whh1, bih1, bhh1,
                     cnt0, cnt1, h0s, h1s, (bx - 8) * 64, smem);
        head_phase(Wout, bout, h1s + 3 * 8192, out, (bx - 8) * 16, cnt1, smem);
    }
}

extern "C" void kernel_launch(void* const* d_in, const int* in_sizes, int n_in,
                              void* d_out, int out_size, void* d_ws, size_t ws_size,
                              hipStream_t stream) {
    const float* x     = (const float*)d_in[0];
    const float* h0i   = (const float*)d_in[1];
    const float* Wih0  = (const float*)d_in[2];
    const float* bih0  = (const float*)d_in[3];
    const float* Whh0  = (const float*)d_in[4];
    const float* bhh0  = (const float*)d_in[5];
    const float* Wih1  = (const float*)d_in[6];
    const float* bih1  = (const float*)d_in[7];
    const float* Whh1  = (const float*)d_in[8];
    const float* bhh1  = (const float*)d_in[9];
    const float* Wout  = (const float*)d_in[10];
    const float* bout  = (const float*)d_in[11];
    float* out = (float*)d_out;

    int* cnt  = (int*)d_ws;                             // 256B counter header
    u64* hbuf = (u64*)((char*)d_ws + 256);              // 2 x 4 slots x 8192 u64 = 512KB
    u16* XB   = (u16*)((char*)d_ws + (1 << 20));        // 64MB bf16 [T][B][H]

    hipMemsetAsync(d_ws, 0, 256, stream);
    xproj_kernel<<<256, 512, 0, stream>>>(x, Wih0, bih0, bhh0, (u64*)XB);

    void* args[] = { &XB, &h0i, &Whh0, &Wih1, &bih1, &Whh1, &bhh1,
                     &Wout, &bout, &out, &cnt, &hbuf };
    hipLaunchCooperativeKernel((const void*)rnn_persist, dim3(16), dim3(512),
                               args, 0, stream);
}